// Round 1
// baseline (1262.170 us; speedup 1.0000x reference)
//
#include <hip/hip_runtime.h>

#define BATCH 1024
#define SEQ   1024
#define FDIM  36
#define HID   20
#define G3    60

__device__ __forceinline__ float fast_sigmoid(float x){
    return __builtin_amdgcn_rcpf(1.0f + __expf(-x));
}
__device__ __forceinline__ float fast_tanh(float x){
    // tanh(x) = 1 - 2/(1+exp(2x)); saturates correctly for large |x|
    return fmaf(-2.0f, __builtin_amdgcn_rcpf(1.0f + __expf(2.0f*x)), 1.0f);
}

// ---------------- Kernel 1: embedding lookup + concat -> origin ----------------
// origin row = [x(12) | e0(4) | e1(4) | e2(8) | e3(8)] = 36 floats = 9 float4s.
__global__ void embed_kernel(const float* __restrict__ x,
                             const int* __restrict__ oh,
                             const float* __restrict__ e0,
                             const float* __restrict__ e1,
                             const float* __restrict__ e2,
                             const float* __restrict__ e3,
                             float4* __restrict__ origin4)
{
    int idx = blockIdx.x * blockDim.x + threadIdx.x;
    if (idx >= BATCH*SEQ*9) return;
    int bs = idx / 9;
    int q  = idx - bs*9;
    float4 v;
    if (q < 3) {
        v = ((const float4*)x)[bs*3 + q];
    } else if (q == 3) {
        v = ((const float4*)e0)[oh[bs*4+0]];
    } else if (q == 4) {
        v = ((const float4*)e1)[oh[bs*4+1]];
    } else if (q < 7) {
        v = ((const float4*)e2)[oh[bs*4+2]*2 + (q-5)];
    } else {
        v = ((const float4*)e3)[oh[bs*4+3]*2 + (q-7)];
    }
    origin4[idx] = v;
}

// ---------------- Kernel 2: encoder GRU + decoder GRU, one wave per batch ----------------
// Lane k in [0,60): owns gate-row k (rows 0..19=r, 20..39=z, 40..59=n).
// Weight rows held in per-lane VGPRs. Hidden state broadcast via v_readlane -> uniform regs.
// No barriers, no cross-wave communication. 1024 waves total = 1 per SIMD.

#define READLANE_F(v, u) __int_as_float(__builtin_amdgcn_readlane(__float_as_int(v), (u)))

__global__ __launch_bounds__(256, 1)
void gru_kernel(const float* __restrict__ xin,
                const float* __restrict__ Wih1g, const float* __restrict__ Whh1g,
                const float* __restrict__ bih1g, const float* __restrict__ bhh1g,
                const float* __restrict__ Wih2g, const float* __restrict__ Whh2g,
                const float* __restrict__ bih2g, const float* __restrict__ bhh2g,
                const float* __restrict__ Wfcg,  const float* __restrict__ bfcg,
                float* __restrict__ out2)
{
    __shared__ __align__(16) float xsh[4][64];   // per-wave x broadcast buffer (decoder)
    const int lane  = threadIdx.x & 63;
    const int wslot = threadIdx.x >> 6;
    int wv = blockIdx.x * 4 + wslot;
    const int b = __builtin_amdgcn_readfirstlane(wv);   // wave-uniform batch index

    const int k  = lane < G3   ? lane : G3-1;    // clamp for weight loads
    const int kf = lane < FDIM ? lane : FDIM-1;

    // -------- per-lane weight rows in registers --------
    float wih1[FDIM], whh1[HID], wih2[FDIM], whh2[HID], wfc[HID];
    #pragma unroll
    for (int j=0;j<FDIM;j++) wih1[j] = Wih1g[k*FDIM+j];
    #pragma unroll
    for (int u=0;u<HID;u++)  whh1[u] = Whh1g[k*HID+u];
    #pragma unroll
    for (int j=0;j<FDIM;j++) wih2[j] = Wih2g[k*FDIM+j];
    #pragma unroll
    for (int u=0;u<HID;u++)  whh2[u] = Whh2g[k*HID+u];
    #pragma unroll
    for (int u=0;u<HID;u++)  wfc[u]  = Wfcg[kf*HID+u];
    const float bi1 = bih1g[k], bh1 = bhh1g[k];
    const float bi2 = bih2g[k], bh2 = bhh2g[k];
    const float bf  = bfcg[kf];

    float hs[HID];                 // uniform copy of hidden state (readlane'd)
    #pragma unroll
    for (int u=0;u<HID;u++) hs[u] = 0.0f;
    float hv = 0.0f;               // per-lane h[lane] (valid for lane<20)

    const float* xbase = xin + (size_t)b * SEQ * FDIM;   // uniform -> scalar loads

    // -------- encoder step: gates + h update, h broadcast via readlane --------
#define ENC_STEP(XS) do {                                                    \
        float g0=bi1,g1=0.f,g2=0.f,g3=0.f;                                   \
        _Pragma("unroll")                                                    \
        for (int j=0;j<FDIM;j+=4){                                           \
            g0 = fmaf(wih1[j+0], XS[j+0], g0);                               \
            g1 = fmaf(wih1[j+1], XS[j+1], g1);                               \
            g2 = fmaf(wih1[j+2], XS[j+2], g2);                               \
            g3 = fmaf(wih1[j+3], XS[j+3], g3);                               \
        }                                                                    \
        float gi = (g0+g1)+(g2+g3);                                          \
        float h0a=bh1,h1a=0.f,h2a=0.f,h3a=0.f;                               \
        _Pragma("unroll")                                                    \
        for (int u=0;u<HID;u+=4){                                            \
            h0a = fmaf(whh1[u+0], hs[u+0], h0a);                             \
            h1a = fmaf(whh1[u+1], hs[u+1], h1a);                             \
            h2a = fmaf(whh1[u+2], hs[u+2], h2a);                             \
            h3a = fmaf(whh1[u+3], hs[u+3], h3a);                             \
        }                                                                    \
        float gh = (h0a+h1a)+(h2a+h3a);                                      \
        float v  = gi + gh;                                                  \
        float vz = __shfl(v,  (lane+20)&63);                                 \
        float in_= __shfl(gi, (lane+40)&63);                                 \
        float hn = __shfl(gh, (lane+40)&63);                                 \
        float r = fast_sigmoid(v);                                           \
        float z = fast_sigmoid(vz);                                          \
        float n = fast_tanh(fmaf(r, hn, in_));                               \
        hv = n + z*(hv - n);                                                 \
        _Pragma("unroll")                                                    \
        for (int u=0;u<HID;u++) hs[u] = READLANE_F(hv, u);                   \
    } while(0)

    // -------- encoder loop, x double-buffered one step ahead --------
    float xa[FDIM], xb[FDIM];
    #pragma unroll
    for (int j=0;j<FDIM;j++) xa[j] = xbase[j];
    for (int t=0; t<SEQ; t+=2){
        const float* p1 = xbase + (size_t)(t+1)*FDIM;
        #pragma unroll
        for (int j=0;j<FDIM;j++) xb[j] = p1[j];
        ENC_STEP(xa);
        const float* p2 = xbase + (size_t)(t+2)*FDIM;   // last iter reads 1 row past
        #pragma unroll                                   // origin: still inside d_out, unused
        for (int j=0;j<FDIM;j++) xa[j] = p2[j];
        ENC_STEP(xb);
    }

    // -------- handoff: h = tanh(h_last), x0 = tanh(h @ Wfc^T + bfc) --------
    float hvd = fast_tanh(hv);
    #pragma unroll
    for (int u=0;u<HID;u++) hs[u] = READLANE_F(hvd, u);

    float* orow = out2 + ((size_t)b*SEQ + (SEQ-1))*FDIM;  // step d writes row S-1-d

    float xv;
    {
        float a0=bf,a1=0.f,a2=0.f,a3=0.f;
        #pragma unroll
        for (int u=0;u<HID;u+=4){
            a0=fmaf(wfc[u+0],hs[u+0],a0);
            a1=fmaf(wfc[u+1],hs[u+1],a1);
            a2=fmaf(wfc[u+2],hs[u+2],a2);
            a3=fmaf(wfc[u+3],hs[u+3],a3);
        }
        xv = fast_tanh((a0+a1)+(a2+a3));
    }
    if (lane < FDIM) orow[lane] = xv;
    xsh[wslot][lane] = xv;                       // intra-wave broadcast (no barrier needed)
    float4 xs4[9];
    #pragma unroll
    for (int q=0;q<9;q++) xs4[q] = ((const float4*)xsh[wslot])[q];

    // -------- decoder loop --------
    for (int d=1; d<SEQ; ++d){
        orow -= FDIM;
        float g0=bi2,g1=0.f,g2=0.f,g3=0.f;
        #pragma unroll
        for (int q=0;q<9;q++){
            g0=fmaf(wih2[4*q+0], xs4[q].x, g0);
            g1=fmaf(wih2[4*q+1], xs4[q].y, g1);
            g2=fmaf(wih2[4*q+2], xs4[q].z, g2);
            g3=fmaf(wih2[4*q+3], xs4[q].w, g3);
        }
        float gi=(g0+g1)+(g2+g3);
        float h0a=bh2,h1a=0.f,h2a=0.f,h3a=0.f;
        #pragma unroll
        for (int u=0;u<HID;u+=4){
            h0a=fmaf(whh2[u+0],hs[u+0],h0a);
            h1a=fmaf(whh2[u+1],hs[u+1],h1a);
            h2a=fmaf(whh2[u+2],hs[u+2],h2a);
            h3a=fmaf(whh2[u+3],hs[u+3],h3a);
        }
        float gh=(h0a+h1a)+(h2a+h3a);
        float v  = gi+gh;
        float vz = __shfl(v, (lane+20)&63);
        float in_= __shfl(gi,(lane+40)&63);
        float hn = __shfl(gh,(lane+40)&63);
        float r = fast_sigmoid(v);
        float z = fast_sigmoid(vz);
        float n = fast_tanh(fmaf(r,hn,in_));
        float hraw = n + z*(hvd - n);
        hvd = fast_tanh(hraw);                    // decoder applies extra tanh to h
        #pragma unroll
        for (int u=0;u<HID;u++) hs[u] = READLANE_F(hvd, u);
        float a0=bf,a1=0.f,a2=0.f,a3=0.f;
        #pragma unroll
        for (int u=0;u<HID;u+=4){
            a0=fmaf(wfc[u+0],hs[u+0],a0);
            a1=fmaf(wfc[u+1],hs[u+1],a1);
            a2=fmaf(wfc[u+2],hs[u+2],a2);
            a3=fmaf(wfc[u+3],hs[u+3],a3);
        }
        xv = fast_tanh((a0+a1)+(a2+a3));
        if (lane < FDIM) orow[lane] = xv;
        xsh[wslot][lane] = xv;
        #pragma unroll
        for (int q=0;q<9;q++) xs4[q] = ((const float4*)xsh[wslot])[q];
    }
}

extern "C" void kernel_launch(void* const* d_in, const int* in_sizes, int n_in,
                              void* d_out, int out_size, void* d_ws, size_t ws_size,
                              hipStream_t stream) {
    const float* x    = (const float*)d_in[0];
    const int*   oh   = (const int*)d_in[1];
    const float* e0   = (const float*)d_in[2];
    const float* e1   = (const float*)d_in[3];
    const float* e2   = (const float*)d_in[4];
    const float* e3   = (const float*)d_in[5];
    const float* Wih1 = (const float*)d_in[6];
    const float* Whh1 = (const float*)d_in[7];
    const float* bih1 = (const float*)d_in[8];
    const float* bhh1 = (const float*)d_in[9];
    const float* Wih2 = (const float*)d_in[10];
    const float* Whh2 = (const float*)d_in[11];
    const float* bih2 = (const float*)d_in[12];
    const float* bhh2 = (const float*)d_in[13];
    const float* Wfc  = (const float*)d_in[14];
    const float* bfc  = (const float*)d_in[15];

    float* out    = (float*)d_out;
    float* origin = out;                                   // output 0: (B,S,F)
    float* out2   = out + (size_t)BATCH*SEQ*FDIM;          // output 1: (B,S,F)

    embed_kernel<<<(BATCH*SEQ*9 + 255)/256, 256, 0, stream>>>(x, oh, e0, e1, e2, e3,
                                                              (float4*)origin);
    gru_kernel<<<(BATCH*64)/256, 256, 0, stream>>>(origin,
                                                   Wih1, Whh1, bih1, bhh1,
                                                   Wih2, Whh2, bih2, bhh2,
                                                   Wfc, bfc, out2);
}

// Round 2
// 1258.101 us; speedup vs baseline: 1.0032x; 1.0032x over previous
//
#include <hip/hip_runtime.h>

#define BATCH 1024
#define SEQ   1024
#define FDIM  36
#define HID   20
#define G3    60
#define GIPAD 60   // floats per precomputed-gi row

__device__ __forceinline__ float fast_sigmoid(float x){
    return __builtin_amdgcn_rcpf(1.0f + __expf(-x));
}
__device__ __forceinline__ float fast_tanh(float x){
    // tanh(x) = 1 - 2/(1+exp(2x)); saturates correctly for large |x|
    return fmaf(-2.0f, __builtin_amdgcn_rcpf(1.0f + __expf(2.0f*x)), 1.0f);
}

#define READLANE_F(v, u) __int_as_float(__builtin_amdgcn_readlane(__float_as_int(v), (u)))

// ---------------- Kernel 1: embed/concat -> origin, fused with gi = Wih1@x + bih1 ----------
// One wave per chunk of rows; lane j<36 builds origin col j; lane k<60 computes gi row-elem k.
// High occupancy (8 waves/SIMD) hides all gather latency via TLP.
template<bool WRITE_GI>
__global__ __launch_bounds__(256, 1)
void prep_kernel(const float* __restrict__ x,
                 const int* __restrict__ oh,
                 const float* __restrict__ e0, const float* __restrict__ e1,
                 const float* __restrict__ e2, const float* __restrict__ e3,
                 const float* __restrict__ Wih1g, const float* __restrict__ bih1g,
                 float* __restrict__ origin, float* __restrict__ gibuf,
                 int rows_per_wave)
{
    const int lane  = threadIdx.x & 63;
    const int wslot = threadIdx.x >> 6;
    const int w = blockIdx.x * 4 + wslot;
    const long r0 = (long)w * rows_per_wave;

    // per-lane gather descriptor (constant across rows)
    const int j = lane;
    const float* tbl; int ohc, dim, sub;
    if (j < 16)      { tbl = e0; ohc = 0; dim = 4; sub = j - 12; }
    else if (j < 20) { tbl = e1; ohc = 1; dim = 4; sub = j - 16; }
    else if (j < 28) { tbl = e2; ohc = 2; dim = 8; sub = j - 20; }
    else             { tbl = e3; ohc = 3; dim = 8; sub = j - 28; }
    if (sub < 0) sub = 0;
    if (sub > dim - 1) sub = dim - 1;   // lanes >=36: clamp (values unused)

    const int k = lane < G3 ? lane : G3 - 1;
    float w1[FDIM]; float bi;
    if (WRITE_GI) {
        #pragma unroll
        for (int jj = 0; jj < FDIM; jj++) w1[jj] = Wih1g[k * FDIM + jj];
        bi = bih1g[k];
    }

    for (int i = 0; i < rows_per_wave; ++i) {
        const long row = r0 + i;
        float val;
        if (j < 12) val = x[row * 12 + j];
        else        val = tbl[oh[row * 4 + ohc] * dim + sub];
        if (lane < FDIM) origin[row * FDIM + lane] = val;
        if (WRITE_GI) {
            float a0 = bi, a1 = 0.f, a2 = 0.f, a3 = 0.f;
            #pragma unroll
            for (int jj = 0; jj < FDIM; jj += 4) {
                a0 = fmaf(w1[jj + 0], READLANE_F(val, jj + 0), a0);
                a1 = fmaf(w1[jj + 1], READLANE_F(val, jj + 1), a1);
                a2 = fmaf(w1[jj + 2], READLANE_F(val, jj + 2), a2);
                a3 = fmaf(w1[jj + 3], READLANE_F(val, jj + 3), a3);
            }
            if (lane < G3) gibuf[row * GIPAD + lane] = (a0 + a1) + (a2 + a3);
        }
    }
}

// ---------------- Kernel 2: encoder GRU (gi-streaming) + decoder GRU ----------------
// One wave per batch element; lane k<60 owns gate-row k (0..19=r, 20..39=z, 40..59=n).
// No LDS, no barriers. Cross-gate values via ds_bpermute (__shfl); h/x broadcast via readlane.
template<bool USE_GI>
__global__ __launch_bounds__(256, 1)
void gru_kernel(const float* __restrict__ xin,     // origin (fallback path)
                const float* __restrict__ gibuf,   // precomputed gi (main path)
                const float* __restrict__ Wih1g, const float* __restrict__ Whh1g,
                const float* __restrict__ bih1g, const float* __restrict__ bhh1g,
                const float* __restrict__ Wih2g, const float* __restrict__ Whh2g,
                const float* __restrict__ bih2g, const float* __restrict__ bhh2g,
                const float* __restrict__ Wfcg,  const float* __restrict__ bfcg,
                float* __restrict__ out2)
{
    const int lane  = threadIdx.x & 63;
    const int wslot = threadIdx.x >> 6;
    const int b = __builtin_amdgcn_readfirstlane(blockIdx.x * 4 + wslot);

    const int k  = lane < G3   ? lane : G3 - 1;
    const int kf = lane < FDIM ? lane : FDIM - 1;

    float whh1[HID], wih2[FDIM], whh2[HID], wfc[HID];
    #pragma unroll
    for (int u = 0; u < HID; u++) whh1[u] = Whh1g[k * HID + u];
    #pragma unroll
    for (int jj = 0; jj < FDIM; jj++) wih2[jj] = Wih2g[k * FDIM + jj];
    #pragma unroll
    for (int u = 0; u < HID; u++) whh2[u] = Whh2g[k * HID + u];
    #pragma unroll
    for (int u = 0; u < HID; u++) wfc[u] = Wfcg[kf * HID + u];
    const float bh1 = bhh1g[k];
    const float bi2 = bih2g[k], bh2 = bhh2g[k];
    const float bf  = bfcg[kf];

    float hs[HID];
    #pragma unroll
    for (int u = 0; u < HID; u++) hs[u] = 0.0f;
    float hv = 0.0f;

    // ---------------- encoder ----------------
    if (USE_GI) {
        const float* gb = gibuf + (size_t)b * SEQ * GIPAD + k;
        float gq[8];
        #pragma unroll
        for (int u = 0; u < 8; u++) gq[u] = gb[(size_t)u * GIPAD];
        for (int t = 0; t < SEQ; t += 8) {
            #pragma unroll
            for (int u = 0; u < 8; u++) {
                float giv = gq[u];
                int nr = t + u + 8; nr = nr < SEQ ? nr : SEQ - 1;   // harmless re-read at tail
                gq[u] = gb[(size_t)nr * GIPAD];
                float h0 = bh1, h1 = 0.f, h2 = 0.f, h3 = 0.f;
                #pragma unroll
                for (int uu = 0; uu < HID; uu += 4) {
                    h0 = fmaf(whh1[uu + 0], hs[uu + 0], h0);
                    h1 = fmaf(whh1[uu + 1], hs[uu + 1], h1);
                    h2 = fmaf(whh1[uu + 2], hs[uu + 2], h2);
                    h3 = fmaf(whh1[uu + 3], hs[uu + 3], h3);
                }
                float gh = (h0 + h1) + (h2 + h3);
                float v   = giv + gh;
                float vz  = __shfl(v,   (lane + 20) & 63);
                float in_ = __shfl(giv, (lane + 40) & 63);
                float hn  = __shfl(gh,  (lane + 40) & 63);
                float r = fast_sigmoid(v);
                float z = fast_sigmoid(vz);
                float n = fast_tanh(fmaf(r, hn, in_));
                hv = n + z * (hv - n);
                #pragma unroll
                for (int uu = 0; uu < HID; uu++) hs[uu] = READLANE_F(hv, uu);
            }
        }
    } else {
        // fallback: in-loop input matvec (ws too small for gi)
        float wih1[FDIM]; float bi1;
        #pragma unroll
        for (int jj = 0; jj < FDIM; jj++) wih1[jj] = Wih1g[k * FDIM + jj];
        bi1 = bih1g[k];
        const float* xbase = xin + (size_t)b * SEQ * FDIM;
        float xa[FDIM], xb[FDIM];
        #pragma unroll
        for (int jj = 0; jj < FDIM; jj++) xa[jj] = xbase[jj];
#define ENC_STEP(XS) do {                                                    \
        float g0 = bi1, g1 = 0.f, g2 = 0.f, g3 = 0.f;                        \
        _Pragma("unroll")                                                    \
        for (int jj = 0; jj < FDIM; jj += 4) {                               \
            g0 = fmaf(wih1[jj + 0], XS[jj + 0], g0);                         \
            g1 = fmaf(wih1[jj + 1], XS[jj + 1], g1);                         \
            g2 = fmaf(wih1[jj + 2], XS[jj + 2], g2);                         \
            g3 = fmaf(wih1[jj + 3], XS[jj + 3], g3);                         \
        }                                                                    \
        float gi = (g0 + g1) + (g2 + g3);                                    \
        float h0 = bh1, h1 = 0.f, h2 = 0.f, h3 = 0.f;                        \
        _Pragma("unroll")                                                    \
        for (int uu = 0; uu < HID; uu += 4) {                                \
            h0 = fmaf(whh1[uu + 0], hs[uu + 0], h0);                         \
            h1 = fmaf(whh1[uu + 1], hs[uu + 1], h1);                         \
            h2 = fmaf(whh1[uu + 2], hs[uu + 2], h2);                         \
            h3 = fmaf(whh1[uu + 3], hs[uu + 3], h3);                         \
        }                                                                    \
        float gh = (h0 + h1) + (h2 + h3);                                    \
        float v   = gi + gh;                                                 \
        float vz  = __shfl(v,  (lane + 20) & 63);                            \
        float in_ = __shfl(gi, (lane + 40) & 63);                            \
        float hn  = __shfl(gh, (lane + 40) & 63);                            \
        float r = fast_sigmoid(v);                                           \
        float z = fast_sigmoid(vz);                                          \
        float n = fast_tanh(fmaf(r, hn, in_));                               \
        hv = n + z * (hv - n);                                               \
        _Pragma("unroll")                                                    \
        for (int uu = 0; uu < HID; uu++) hs[uu] = READLANE_F(hv, uu);        \
    } while (0)
        for (int t = 0; t < SEQ; t += 2) {
            const float* p1 = xbase + (size_t)(t + 1) * FDIM;
            #pragma unroll
            for (int jj = 0; jj < FDIM; jj++) xb[jj] = p1[jj];
            ENC_STEP(xa);
            const float* p2 = xbase + (size_t)(t + 2) * FDIM;
            #pragma unroll
            for (int jj = 0; jj < FDIM; jj++) xa[jj] = p2[jj];
            ENC_STEP(xb);
        }
    }

    // ---------------- handoff ----------------
    float hvd = fast_tanh(hv);
    #pragma unroll
    for (int u = 0; u < HID; u++) hs[u] = READLANE_F(hvd, u);

    float* orow = out2 + ((size_t)b * SEQ + (SEQ - 1)) * FDIM;

    float xv;
    {
        float a0 = bf, a1 = 0.f, a2 = 0.f, a3 = 0.f;
        #pragma unroll
        for (int u = 0; u < HID; u += 4) {
            a0 = fmaf(wfc[u + 0], hs[u + 0], a0);
            a1 = fmaf(wfc[u + 1], hs[u + 1], a1);
            a2 = fmaf(wfc[u + 2], hs[u + 2], a2);
            a3 = fmaf(wfc[u + 3], hs[u + 3], a3);
        }
        xv = fast_tanh((a0 + a1) + (a2 + a3));
    }
    if (lane < FDIM) orow[lane] = xv;
    float xs[FDIM];
    #pragma unroll
    for (int jj = 0; jj < FDIM; jj++) xs[jj] = READLANE_F(xv, jj);

    // ---------------- decoder ----------------
    for (int d = 1; d < SEQ; ++d) {
        orow -= FDIM;
        float g0 = bi2, g1 = 0.f, g2 = 0.f, g3 = 0.f;
        #pragma unroll
        for (int jj = 0; jj < FDIM; jj += 4) {
            g0 = fmaf(wih2[jj + 0], xs[jj + 0], g0);
            g1 = fmaf(wih2[jj + 1], xs[jj + 1], g1);
            g2 = fmaf(wih2[jj + 2], xs[jj + 2], g2);
            g3 = fmaf(wih2[jj + 3], xs[jj + 3], g3);
        }
        float gi = (g0 + g1) + (g2 + g3);
        float h0 = bh2, h1 = 0.f, h2 = 0.f, h3 = 0.f;
        #pragma unroll
        for (int u = 0; u < HID; u += 4) {
            h0 = fmaf(whh2[u + 0], hs[u + 0], h0);
            h1 = fmaf(whh2[u + 1], hs[u + 1], h1);
            h2 = fmaf(whh2[u + 2], hs[u + 2], h2);
            h3 = fmaf(whh2[u + 3], hs[u + 3], h3);
        }
        float gh = (h0 + h1) + (h2 + h3);
        float v   = gi + gh;
        float vz  = __shfl(v,  (lane + 20) & 63);
        float in_ = __shfl(gi, (lane + 40) & 63);
        float hn  = __shfl(gh, (lane + 40) & 63);
        float r = fast_sigmoid(v);
        float z = fast_sigmoid(vz);
        float n = fast_tanh(fmaf(r, hn, in_));
        float hraw = n + z * (hvd - n);
        hvd = fast_tanh(hraw);
        #pragma unroll
        for (int u = 0; u < HID; u++) hs[u] = READLANE_F(hvd, u);
        float a0 = bf, a1 = 0.f, a2 = 0.f, a3 = 0.f;
        #pragma unroll
        for (int u = 0; u < HID; u += 4) {
            a0 = fmaf(wfc[u + 0], hs[u + 0], a0);
            a1 = fmaf(wfc[u + 1], hs[u + 1], a1);
            a2 = fmaf(wfc[u + 2], hs[u + 2], a2);
            a3 = fmaf(wfc[u + 3], hs[u + 3], a3);
        }
        xv = fast_tanh((a0 + a1) + (a2 + a3));
        if (lane < FDIM) orow[lane] = xv;
        #pragma unroll
        for (int jj = 0; jj < FDIM; jj++) xs[jj] = READLANE_F(xv, jj);
    }
}

extern "C" void kernel_launch(void* const* d_in, const int* in_sizes, int n_in,
                              void* d_out, int out_size, void* d_ws, size_t ws_size,
                              hipStream_t stream) {
    const float* x    = (const float*)d_in[0];
    const int*   oh   = (const int*)d_in[1];
    const float* e0   = (const float*)d_in[2];
    const float* e1   = (const float*)d_in[3];
    const float* e2   = (const float*)d_in[4];
    const float* e3   = (const float*)d_in[5];
    const float* Wih1 = (const float*)d_in[6];
    const float* Whh1 = (const float*)d_in[7];
    const float* bih1 = (const float*)d_in[8];
    const float* bhh1 = (const float*)d_in[9];
    const float* Wih2 = (const float*)d_in[10];
    const float* Whh2 = (const float*)d_in[11];
    const float* bih2 = (const float*)d_in[12];
    const float* bhh2 = (const float*)d_in[13];
    const float* Wfc  = (const float*)d_in[14];
    const float* bfc  = (const float*)d_in[15];

    float* out    = (float*)d_out;
    float* origin = out;                                   // output 0: (B,S,F)
    float* out2   = out + (size_t)BATCH * SEQ * FDIM;      // output 1: (B,S,F)
    float* gibuf  = (float*)d_ws;

    const size_t gi_bytes = (size_t)BATCH * SEQ * GIPAD * sizeof(float);
    const int rows_per_wave = (BATCH * SEQ) / (2048 * 4);  // = 128

    if (ws_size >= gi_bytes) {
        prep_kernel<true><<<2048, 256, 0, stream>>>(x, oh, e0, e1, e2, e3,
                                                    Wih1, bih1, origin, gibuf,
                                                    rows_per_wave);
        gru_kernel<true><<<(BATCH * 64) / 256, 256, 0, stream>>>(origin, gibuf,
            Wih1, Whh1, bih1, bhh1, Wih2, Whh2, bih2, bhh2, Wfc, bfc, out2);
    } else {
        prep_kernel<false><<<2048, 256, 0, stream>>>(x, oh, e0, e1, e2, e3,
                                                     Wih1, bih1, origin, gibuf,
                                                     rows_per_wave);
        gru_kernel<false><<<(BATCH * 64) / 256, 256, 0, stream>>>(origin, gibuf,
            Wih1, Whh1, bih1, bhh1, Wih2, Whh2, bih2, bhh2, Wfc, bfc, out2);
    }
}

// Round 3
// 1076.877 us; speedup vs baseline: 1.1721x; 1.1683x over previous
//
#include <hip/hip_runtime.h>

#define BATCH 1024
#define SEQ   1024
#define FDIM  36
#define HID   20
#define G3    60
#define GIPAD 60
#define NROWS (BATCH*SEQ)

typedef float v2f __attribute__((ext_vector_type(2)));

__device__ __forceinline__ float fast_sigmoid(float x){
    return __builtin_amdgcn_rcpf(1.0f + __expf(-x));
}
__device__ __forceinline__ float fast_tanh(float x){
    return fmaf(-2.0f, __builtin_amdgcn_rcpf(1.0f + __expf(2.0f*x)), 1.0f);
}

#define READLANE_F(v, u) __int_as_float(__builtin_amdgcn_readlane(__float_as_int(v), (u)))

// ---------------- Kernel 1: embed/concat -> origin, fused with gi = Wih1@x + bih1 ----------
// 64 rows per wave, ring-prefetched: oh 16 rows ahead, gathered val 8 rows ahead.
// Branch-free gather: per-lane base pointer + cndmask'd offset -> one load per lane per row.
template<bool WRITE_GI>
__global__ __launch_bounds__(256, 1)
void prep_kernel(const float* __restrict__ x,
                 const int* __restrict__ oh,
                 const float* __restrict__ e0, const float* __restrict__ e1,
                 const float* __restrict__ e2, const float* __restrict__ e3,
                 const float* __restrict__ Wih1g, const float* __restrict__ bih1g,
                 float* __restrict__ origin, float* __restrict__ gibuf)
{
    const int lane  = threadIdx.x & 63;
    const int wslot = threadIdx.x >> 6;
    const int w = blockIdx.x * 4 + wslot;
    const int ROWS = 64;
    const int r0 = w * ROWS;

    // per-lane gather descriptor (computed once; uniform control flow thereafter)
    const int j = lane;
    const float* tbl; int ohc, eshift, sub;
    if (j < 16)      { tbl = e0; ohc = 0; eshift = 2; sub = j - 12; }
    else if (j < 20) { tbl = e1; ohc = 1; eshift = 2; sub = j - 16; }
    else if (j < 28) { tbl = e2; ohc = 2; eshift = 3; sub = j - 20; }
    else             { tbl = e3; ohc = 3; eshift = 3; sub = j - 28; }
    if (sub < 0) sub = 0;
    if (sub > 7) sub = 7;
    const bool from_x = (j < 12);
    const float* pa = from_x ? (x + j) : (tbl + sub);   // per-lane base

    float w1[FDIM]; float bi = 0.f;
    const int k = lane < G3 ? lane : G3 - 1;
    if (WRITE_GI) {
        #pragma unroll
        for (int jj = 0; jj < FDIM; jj++) w1[jj] = Wih1g[k * FDIM + jj];
        bi = bih1g[k];
    }

    int   ohq[8];
    float valq[8];
    // prologue: oh for rows r0..r0+7
    #pragma unroll
    for (int s = 0; s < 8; s++) {
        int r = r0 + s; if (r >= NROWS) r = NROWS - 1;
        ohq[s] = oh[r * 4 + ohc];
    }
    // val for rows r0..r0+7; refill oh with rows r0+8..r0+15
    #pragma unroll
    for (int s = 0; s < 8; s++) {
        int r = r0 + s; if (r >= NROWS) r = NROWS - 1;
        int off = from_x ? (r * 12) : (ohq[s] << eshift);
        valq[s] = pa[off];
        int r2 = r0 + s + 8; if (r2 >= NROWS) r2 = NROWS - 1;
        ohq[s] = oh[r2 * 4 + ohc];
    }

    for (int i = 0; i < ROWS; i++) {
        const int s = i & 7;
        const float val = valq[s];
        // prefetch val for row i+8 (oh already in ring), then oh for row i+16
        int rv = r0 + i + 8;  if (rv >= NROWS) rv = NROWS - 1;
        int off = from_x ? (rv * 12) : (ohq[s] << eshift);
        valq[s] = pa[off];
        int ro = r0 + i + 16; if (ro >= NROWS) ro = NROWS - 1;
        ohq[s] = oh[ro * 4 + ohc];

        const int row = r0 + i;
        if (lane < FDIM) origin[row * FDIM + lane] = val;
        if (WRITE_GI) {
            float a0 = bi, a1 = 0.f, a2 = 0.f, a3 = 0.f;
            #pragma unroll
            for (int jj = 0; jj < FDIM; jj += 4) {
                a0 = fmaf(w1[jj + 0], READLANE_F(val, jj + 0), a0);
                a1 = fmaf(w1[jj + 1], READLANE_F(val, jj + 1), a1);
                a2 = fmaf(w1[jj + 2], READLANE_F(val, jj + 2), a2);
                a3 = fmaf(w1[jj + 3], READLANE_F(val, jj + 3), a3);
            }
            if (lane < G3) gibuf[row * GIPAD + lane] = (a0 + a1) + (a2 + a3);
        }
    }
}

// ---------------- Kernel 2: encoder GRU (gi-streaming) + decoder GRU ----------------
// One wave per batch element; lane k<60 owns gate-row k (0..19=r, 20..39=z, 40..59=n).
// h broadcast via readlane (SGPR operands); decoder x broadcast via LDS float2 + pk_fma.
template<bool USE_GI>
__global__ __launch_bounds__(256, 1)
void gru_kernel(const float* __restrict__ xin,
                const float* __restrict__ gibuf,
                const float* __restrict__ Wih1g, const float* __restrict__ Whh1g,
                const float* __restrict__ bih1g, const float* __restrict__ bhh1g,
                const float* __restrict__ Wih2g, const float* __restrict__ Whh2g,
                const float* __restrict__ bih2g, const float* __restrict__ bhh2g,
                const float* __restrict__ Wfcg,  const float* __restrict__ bfcg,
                float* __restrict__ out2)
{
    __shared__ __align__(16) float xsh[4][64];
    const int lane  = threadIdx.x & 63;
    const int wslot = threadIdx.x >> 6;
    const int b = __builtin_amdgcn_readfirstlane(blockIdx.x * 4 + wslot);

    const int k  = lane < G3   ? lane : G3 - 1;
    const int kf = lane < FDIM ? lane : FDIM - 1;

    float whh1[HID], whh2[HID], wfc[HID];
    v2f wih2p[FDIM/2];
    #pragma unroll
    for (int u = 0; u < HID; u++) whh1[u] = Whh1g[k * HID + u];
    #pragma unroll
    for (int q = 0; q < FDIM/2; q++) wih2p[q] = ((const v2f*)(Wih2g + k * FDIM))[q];
    #pragma unroll
    for (int u = 0; u < HID; u++) whh2[u] = Whh2g[k * HID + u];
    #pragma unroll
    for (int u = 0; u < HID; u++) wfc[u] = Wfcg[kf * HID + u];
    const float bh1 = bhh1g[k];
    const float bi2 = bih2g[k], bh2 = bhh2g[k];
    const float bf  = bfcg[kf];

    float hs[HID];
    #pragma unroll
    for (int u = 0; u < HID; u++) hs[u] = 0.0f;
    float hv = 0.0f;

    // ---------------- encoder ----------------
    if (USE_GI) {
        const float* gb = gibuf + (size_t)b * SEQ * GIPAD + k;
        float gq[8];
        #pragma unroll
        for (int u = 0; u < 8; u++) gq[u] = gb[(size_t)u * GIPAD];
        for (int t = 0; t < SEQ; t += 8) {
            #pragma unroll
            for (int u = 0; u < 8; u++) {
                float giv = gq[u];
                int nr = t + u + 8; nr = nr < SEQ ? nr : SEQ - 1;
                gq[u] = gb[(size_t)nr * GIPAD];
                float h0 = bh1, h1 = 0.f, h2 = 0.f, h3 = 0.f;
                #pragma unroll
                for (int uu = 0; uu < HID; uu += 4) {
                    h0 = fmaf(whh1[uu + 0], hs[uu + 0], h0);
                    h1 = fmaf(whh1[uu + 1], hs[uu + 1], h1);
                    h2 = fmaf(whh1[uu + 2], hs[uu + 2], h2);
                    h3 = fmaf(whh1[uu + 3], hs[uu + 3], h3);
                }
                float gh = (h0 + h1) + (h2 + h3);
                float v   = giv + gh;
                float vz  = __shfl(v,   (lane + 20) & 63);
                float in_ = __shfl(giv, (lane + 40) & 63);
                float hn  = __shfl(gh,  (lane + 40) & 63);
                float r = fast_sigmoid(v);
                float z = fast_sigmoid(vz);
                float n = fast_tanh(fmaf(r, hn, in_));
                hv = n + z * (hv - n);
                #pragma unroll
                for (int uu = 0; uu < HID; uu++) hs[uu] = READLANE_F(hv, uu);
            }
        }
    } else {
        float wih1[FDIM]; float bi1;
        #pragma unroll
        for (int jj = 0; jj < FDIM; jj++) wih1[jj] = Wih1g[k * FDIM + jj];
        bi1 = bih1g[k];
        const float* xbase = xin + (size_t)b * SEQ * FDIM;
        float xa[FDIM], xb[FDIM];
        #pragma unroll
        for (int jj = 0; jj < FDIM; jj++) xa[jj] = xbase[jj];
#define ENC_STEP(XS) do {                                                    \
        float g0 = bi1, g1 = 0.f, g2 = 0.f, g3 = 0.f;                        \
        _Pragma("unroll")                                                    \
        for (int jj = 0; jj < FDIM; jj += 4) {                               \
            g0 = fmaf(wih1[jj + 0], XS[jj + 0], g0);                         \
            g1 = fmaf(wih1[jj + 1], XS[jj + 1], g1);                         \
            g2 = fmaf(wih1[jj + 2], XS[jj + 2], g2);                         \
            g3 = fmaf(wih1[jj + 3], XS[jj + 3], g3);                         \
        }                                                                    \
        float gi = (g0 + g1) + (g2 + g3);                                    \
        float h0 = bh1, h1 = 0.f, h2 = 0.f, h3 = 0.f;                        \
        _Pragma("unroll")                                                    \
        for (int uu = 0; uu < HID; uu += 4) {                                \
            h0 = fmaf(whh1[uu + 0], hs[uu + 0], h0);                         \
            h1 = fmaf(whh1[uu + 1], hs[uu + 1], h1);                         \
            h2 = fmaf(whh1[uu + 2], hs[uu + 2], h2);                         \
            h3 = fmaf(whh1[uu + 3], hs[uu + 3], h3);                         \
        }                                                                    \
        float gh = (h0 + h1) + (h2 + h3);                                    \
        float v   = gi + gh;                                                 \
        float vz  = __shfl(v,  (lane + 20) & 63);                            \
        float in_ = __shfl(gi, (lane + 40) & 63);                            \
        float hn  = __shfl(gh, (lane + 40) & 63);                            \
        float r = fast_sigmoid(v);                                           \
        float z = fast_sigmoid(vz);                                          \
        float n = fast_tanh(fmaf(r, hn, in_));                               \
        hv = n + z * (hv - n);                                               \
        _Pragma("unroll")                                                    \
        for (int uu = 0; uu < HID; uu++) hs[uu] = READLANE_F(hv, uu);        \
    } while (0)
        for (int t = 0; t < SEQ; t += 2) {
            const float* p1 = xbase + (size_t)(t + 1) * FDIM;
            #pragma unroll
            for (int jj = 0; jj < FDIM; jj++) xb[jj] = p1[jj];
            ENC_STEP(xa);
            const float* p2 = xbase + (size_t)(t + 2) * FDIM;
            #pragma unroll
            for (int jj = 0; jj < FDIM; jj++) xa[jj] = p2[jj];
            ENC_STEP(xb);
        }
    }

    // ---------------- handoff ----------------
    float hvd = fast_tanh(hv);
    #pragma unroll
    for (int u = 0; u < HID; u++) hs[u] = READLANE_F(hvd, u);

    float* orow = out2 + ((size_t)b * SEQ + (SEQ - 1)) * FDIM;

    float xv;
    {
        float a0 = bf, a1 = 0.f, a2 = 0.f, a3 = 0.f;
        #pragma unroll
        for (int u = 0; u < HID; u += 4) {
            a0 = fmaf(wfc[u + 0], hs[u + 0], a0);
            a1 = fmaf(wfc[u + 1], hs[u + 1], a1);
            a2 = fmaf(wfc[u + 2], hs[u + 2], a2);
            a3 = fmaf(wfc[u + 3], hs[u + 3], a3);
        }
        xv = fast_tanh((a0 + a1) + (a2 + a3));
    }
    if (lane < FDIM) orow[lane] = xv;
    xsh[wslot][lane] = xv;     // intra-wave broadcast buffer (no barrier: same wave)

    // ---------------- decoder ----------------
    const v2f* xp = (const v2f*)xsh[wslot];
    for (int d = 1; d < SEQ; ++d) {
        orow -= FDIM;
        // read back x (LDS, broadcast) -- latency hidden by the whh2 dot below
        v2f xs2[FDIM/2];
        #pragma unroll
        for (int q = 0; q < FDIM/2; q++) xs2[q] = xp[q];
        // gh2 = Whh2 . h  (SGPR-operand scalar FMAs; independent of xs2)
        float h0 = bh2, h1 = 0.f, h2 = 0.f, h3 = 0.f;
        #pragma unroll
        for (int u = 0; u < HID; u += 4) {
            h0 = fmaf(whh2[u + 0], hs[u + 0], h0);
            h1 = fmaf(whh2[u + 1], hs[u + 1], h1);
            h2 = fmaf(whh2[u + 2], hs[u + 2], h2);
            h3 = fmaf(whh2[u + 3], hs[u + 3], h3);
        }
        float gh = (h0 + h1) + (h2 + h3);
        // gi2 = Wih2 . x  (packed fp32 FMAs)
        v2f accA = {bi2, 0.f}, accB = {0.f, 0.f};
        #pragma unroll
        for (int q = 0; q < FDIM/2; q += 2) {
            accA = __builtin_elementwise_fma(wih2p[q],     xs2[q],     accA);
            accB = __builtin_elementwise_fma(wih2p[q + 1], xs2[q + 1], accB);
        }
        float gi = (accA.x + accB.x) + (accA.y + accB.y);
        float v   = gi + gh;
        float vz  = __shfl(v,  (lane + 20) & 63);
        float in_ = __shfl(gi, (lane + 40) & 63);
        float hn  = __shfl(gh, (lane + 40) & 63);
        float r = fast_sigmoid(v);
        float z = fast_sigmoid(vz);
        float n = fast_tanh(fmaf(r, hn, in_));
        float hraw = n + z * (hvd - n);
        hvd = fast_tanh(hraw);
        #pragma unroll
        for (int u = 0; u < HID; u++) hs[u] = READLANE_F(hvd, u);
        float a0 = bf, a1 = 0.f, a2 = 0.f, a3 = 0.f;
        #pragma unroll
        for (int u = 0; u < HID; u += 4) {
            a0 = fmaf(wfc[u + 0], hs[u + 0], a0);
            a1 = fmaf(wfc[u + 1], hs[u + 1], a1);
            a2 = fmaf(wfc[u + 2], hs[u + 2], a2);
            a3 = fmaf(wfc[u + 3], hs[u + 3], a3);
        }
        xv = fast_tanh((a0 + a1) + (a2 + a3));
        if (lane < FDIM) orow[lane] = xv;
        xsh[wslot][lane] = xv;
    }
}

extern "C" void kernel_launch(void* const* d_in, const int* in_sizes, int n_in,
                              void* d_out, int out_size, void* d_ws, size_t ws_size,
                              hipStream_t stream) {
    const float* x    = (const float*)d_in[0];
    const int*   oh   = (const int*)d_in[1];
    const float* e0   = (const float*)d_in[2];
    const float* e1   = (const float*)d_in[3];
    const float* e2   = (const float*)d_in[4];
    const float* e3   = (const float*)d_in[5];
    const float* Wih1 = (const float*)d_in[6];
    const float* Whh1 = (const float*)d_in[7];
    const float* bih1 = (const float*)d_in[8];
    const float* bhh1 = (const float*)d_in[9];
    const float* Wih2 = (const float*)d_in[10];
    const float* Whh2 = (const float*)d_in[11];
    const float* bih2 = (const float*)d_in[12];
    const float* bhh2 = (const float*)d_in[13];
    const float* Wfc  = (const float*)d_in[14];
    const float* bfc  = (const float*)d_in[15];

    float* out    = (float*)d_out;
    float* origin = out;
    float* out2   = out + (size_t)BATCH * SEQ * FDIM;
    float* gibuf  = (float*)d_ws;

    const size_t gi_bytes = (size_t)BATCH * SEQ * GIPAD * sizeof(float);
    const int prep_blocks = NROWS / (4 * 64);   // 64 rows per wave, 4 waves per block

    if (ws_size >= gi_bytes) {
        prep_kernel<true><<<prep_blocks, 256, 0, stream>>>(x, oh, e0, e1, e2, e3,
                                                           Wih1, bih1, origin, gibuf);
        gru_kernel<true><<<(BATCH * 64) / 256, 256, 0, stream>>>(origin, gibuf,
            Wih1, Whh1, bih1, bhh1, Wih2, Whh2, bih2, bhh2, Wfc, bfc, out2);
    } else {
        prep_kernel<false><<<prep_blocks, 256, 0, stream>>>(x, oh, e0, e1, e2, e3,
                                                            Wih1, bih1, origin, gibuf);
        gru_kernel<false><<<(BATCH * 64) / 256, 256, 0, stream>>>(origin, gibuf,
            Wih1, Whh1, bih1, bhh1, Wih2, Whh2, bih2, bhh2, Wfc, bfc, out2);
    }
}

// Round 4
// 1020.190 us; speedup vs baseline: 1.2372x; 1.0556x over previous
//
#include <hip/hip_runtime.h>

#define BATCH 1024
#define SEQ   1024
#define FDIM  36
#define HID   20
#define G3    60
#define GIPAD 60
#define NROWS (BATCH*SEQ)
#define PROWS 16   // rows per wave in prep

typedef float v2f __attribute__((ext_vector_type(2)));

__device__ __forceinline__ float fast_sigmoid(float x){
    return __builtin_amdgcn_rcpf(1.0f + __expf(-x));
}
__device__ __forceinline__ float fast_tanh(float x){
    return fmaf(-2.0f, __builtin_amdgcn_rcpf(1.0f + __expf(2.0f*x)), 1.0f);
}

#define READLANE_F(v, u) __int_as_float(__builtin_amdgcn_readlane(__float_as_int(v), (u)))

// ---------------- Kernel 1: embed/concat -> origin, fused gi = Wih1@x + bih1 ----------
// 16 rows per wave. Two flat load phases (16 independent oh loads, then 16 gather loads),
// then per row: LDS broadcast (1 ds_write + 9 broadcast ds_read_b128) + 18 v_pk_fma_f32.
// 65536 waves -> 8 resident/SIMD; latency hidden by TLP, ~80 cyc issue per row.
template<bool WRITE_GI>
__global__ __launch_bounds__(256, 4)
void prep_kernel(const float* __restrict__ x,
                 const int* __restrict__ oh,
                 const float* __restrict__ e0, const float* __restrict__ e1,
                 const float* __restrict__ e2, const float* __restrict__ e3,
                 const float* __restrict__ Wih1g, const float* __restrict__ bih1g,
                 float* __restrict__ origin, float* __restrict__ gibuf)
{
    __shared__ __align__(16) float xsh[4][64];
    const int lane  = threadIdx.x & 63;
    const int wslot = threadIdx.x >> 6;
    const int w = blockIdx.x * 4 + wslot;
    const int r0 = w * PROWS;

    // per-lane gather descriptor
    const int j = lane;
    const float* tbl; int ohc, eshift, sub;
    if (j < 16)      { tbl = e0; ohc = 0; eshift = 2; sub = j - 12; }
    else if (j < 20) { tbl = e1; ohc = 1; eshift = 2; sub = j - 16; }
    else if (j < 28) { tbl = e2; ohc = 2; eshift = 3; sub = j - 20; }
    else             { tbl = e3; ohc = 3; eshift = 3; sub = j - 28; }
    if (sub < 0) sub = 0;
    if (sub > 7) sub = 7;
    const bool from_x = (j < 12);
    const float* pa = from_x ? (x + j) : (tbl + sub);

    v2f w1p[FDIM/2]; float bi = 0.f;
    if (WRITE_GI) {
        const int k = lane < G3 ? lane : G3 - 1;
        #pragma unroll
        for (int q = 0; q < FDIM/2; q++) w1p[q] = ((const v2f*)(Wih1g + k * FDIM))[q];
        bi = bih1g[k];
    }

    // phase 1: all 16 oh loads (independent, pipelined)
    int ohv[PROWS];
    #pragma unroll
    for (int s = 0; s < PROWS; s++) ohv[s] = oh[(r0 + s) * 4 + ohc];
    // phase 2: all 16 gather loads (dependent only on phase 1)
    float valv[PROWS];
    #pragma unroll
    for (int s = 0; s < PROWS; s++) {
        int off = from_x ? ((r0 + s) * 12) : (ohv[s] << eshift);
        valv[s] = pa[off];
    }

    // phase 3: per-row broadcast + dot + stores
    const float4* xp4 = (const float4*)xsh[wslot];
    #pragma unroll
    for (int s = 0; s < PROWS; s++) {
        const int row = r0 + s;
        if (lane < FDIM) origin[row * FDIM + lane] = valv[s];
        if (WRITE_GI) {
            xsh[wslot][lane] = valv[s];              // DS ops in-order within wave
            v2f a0 = {bi, 0.f}, a1 = {0.f, 0.f};
            #pragma unroll
            for (int q = 0; q < 9; q++) {
                float4 xv4 = xp4[q];
                v2f xlo = {xv4.x, xv4.y}, xhi = {xv4.z, xv4.w};
                a0 = __builtin_elementwise_fma(w1p[2*q],     xlo, a0);
                a1 = __builtin_elementwise_fma(w1p[2*q + 1], xhi, a1);
            }
            float g = (a0.x + a1.x) + (a0.y + a1.y);
            if (lane < G3) gibuf[row * GIPAD + lane] = g;
        }
    }
}

// ---------------- Kernel 2: encoder GRU (gi-streaming) + decoder GRU ----------------
// One wave per batch element; lane k<60 owns gate-row k (0..19=r, 20..39=z, 40..59=n).
// h broadcast via readlane (SGPR operands); decoder x broadcast via LDS float2 + pk_fma.
template<bool USE_GI>
__global__ __launch_bounds__(256, 1)
void gru_kernel(const float* __restrict__ xin,
                const float* __restrict__ gibuf,
                const float* __restrict__ Wih1g, const float* __restrict__ Whh1g,
                const float* __restrict__ bih1g, const float* __restrict__ bhh1g,
                const float* __restrict__ Wih2g, const float* __restrict__ Whh2g,
                const float* __restrict__ bih2g, const float* __restrict__ bhh2g,
                const float* __restrict__ Wfcg,  const float* __restrict__ bfcg,
                float* __restrict__ out2)
{
    __shared__ __align__(16) float xsh[4][64];
    const int lane  = threadIdx.x & 63;
    const int wslot = threadIdx.x >> 6;
    const int b = __builtin_amdgcn_readfirstlane(blockIdx.x * 4 + wslot);

    const int k  = lane < G3   ? lane : G3 - 1;
    const int kf = lane < FDIM ? lane : FDIM - 1;

    float whh1[HID], whh2[HID], wfc[HID];
    v2f wih2p[FDIM/2];
    #pragma unroll
    for (int u = 0; u < HID; u++) whh1[u] = Whh1g[k * HID + u];
    #pragma unroll
    for (int q = 0; q < FDIM/2; q++) wih2p[q] = ((const v2f*)(Wih2g + k * FDIM))[q];
    #pragma unroll
    for (int u = 0; u < HID; u++) whh2[u] = Whh2g[k * HID + u];
    #pragma unroll
    for (int u = 0; u < HID; u++) wfc[u] = Wfcg[kf * HID + u];
    const float bh1 = bhh1g[k];
    const float bi2 = bih2g[k], bh2 = bhh2g[k];
    const float bf  = bfcg[kf];

    float hs[HID];
    #pragma unroll
    for (int u = 0; u < HID; u++) hs[u] = 0.0f;
    float hv = 0.0f;

#define GATE_STEP(GIV, BH) do {                                              \
        float h0 = BH, h1 = 0.f, h2 = 0.f, h3 = 0.f;                         \
        _Pragma("unroll")                                                    \
        for (int uu = 0; uu < HID; uu += 4) {                                \
            h0 = fmaf(whh1[uu + 0], hs[uu + 0], h0);                         \
            h1 = fmaf(whh1[uu + 1], hs[uu + 1], h1);                         \
            h2 = fmaf(whh1[uu + 2], hs[uu + 2], h2);                         \
            h3 = fmaf(whh1[uu + 3], hs[uu + 3], h3);                         \
        }                                                                    \
        float gh = (h0 + h1) + (h2 + h3);                                    \
        float v   = (GIV) + gh;                                              \
        float vz  = __shfl(v,    (lane + 20) & 63);                          \
        float in_ = __shfl((GIV),(lane + 40) & 63);                          \
        float hn  = __shfl(gh,   (lane + 40) & 63);                          \
        float r = fast_sigmoid(v);                                           \
        float z = fast_sigmoid(vz);                                          \
        float n = fast_tanh(fmaf(r, hn, in_));                               \
        hv = n + z * (hv - n);                                               \
        _Pragma("unroll")                                                    \
        for (int uu = 0; uu < HID; uu++) hs[uu] = READLANE_F(hv, uu);        \
    } while (0)

    // ---------------- encoder ----------------
    if (USE_GI) {
        const float* gb = gibuf + (size_t)b * SEQ * GIPAD + k;
        float gq[8];
        #pragma unroll
        for (int u = 0; u < 8; u++) gq[u] = gb[(size_t)u * GIPAD];
        for (int t = 0; t < SEQ; t += 8) {
            if (t + 8 < SEQ) {            // wave-uniform branch
                #pragma unroll
                for (int u = 0; u < 8; u++) {
                    float giv = gq[u];
                    gq[u] = gb[(size_t)(t + u + 8) * GIPAD];
                    GATE_STEP(giv, bh1);
                }
            } else {                      // tail: no prefetch, no clamp math
                #pragma unroll
                for (int u = 0; u < 8; u++) {
                    GATE_STEP(gq[u], bh1);
                }
            }
        }
    } else {
        float wih1[FDIM]; float bi1;
        #pragma unroll
        for (int jj = 0; jj < FDIM; jj++) wih1[jj] = Wih1g[k * FDIM + jj];
        bi1 = bih1g[k];
        const float* xbase = xin + (size_t)b * SEQ * FDIM;
        float xa[FDIM];
        for (int t = 0; t < SEQ; t++) {
            const float* p = xbase + (size_t)t * FDIM;
            #pragma unroll
            for (int jj = 0; jj < FDIM; jj++) xa[jj] = p[jj];
            float g0 = bi1, g1 = 0.f, g2 = 0.f, g3 = 0.f;
            #pragma unroll
            for (int jj = 0; jj < FDIM; jj += 4) {
                g0 = fmaf(wih1[jj + 0], xa[jj + 0], g0);
                g1 = fmaf(wih1[jj + 1], xa[jj + 1], g1);
                g2 = fmaf(wih1[jj + 2], xa[jj + 2], g2);
                g3 = fmaf(wih1[jj + 3], xa[jj + 3], g3);
            }
            float giv = (g0 + g1) + (g2 + g3);
            GATE_STEP(giv, bh1);
        }
    }

    // ---------------- handoff ----------------
    float hvd = fast_tanh(hv);
    #pragma unroll
    for (int u = 0; u < HID; u++) hs[u] = READLANE_F(hvd, u);

    float* orow = out2 + ((size_t)b * SEQ + (SEQ - 1)) * FDIM;

    float xv;
    {
        float a0 = bf, a1 = 0.f, a2 = 0.f, a3 = 0.f;
        #pragma unroll
        for (int u = 0; u < HID; u += 4) {
            a0 = fmaf(wfc[u + 0], hs[u + 0], a0);
            a1 = fmaf(wfc[u + 1], hs[u + 1], a1);
            a2 = fmaf(wfc[u + 2], hs[u + 2], a2);
            a3 = fmaf(wfc[u + 3], hs[u + 3], a3);
        }
        xv = fast_tanh((a0 + a1) + (a2 + a3));
    }
    if (lane < FDIM) orow[lane] = xv;
    xsh[wslot][lane] = xv;     // intra-wave broadcast (no barrier: same wave)

    // ---------------- decoder ----------------
    const v2f* xp = (const v2f*)xsh[wslot];
    for (int d = 1; d < SEQ; ++d) {
        orow -= FDIM;
        v2f xs2[FDIM/2];
        #pragma unroll
        for (int q = 0; q < FDIM/2; q++) xs2[q] = xp[q];
        float h0 = bh2, h1 = 0.f, h2 = 0.f, h3 = 0.f;
        #pragma unroll
        for (int u = 0; u < HID; u += 4) {
            h0 = fmaf(whh2[u + 0], hs[u + 0], h0);
            h1 = fmaf(whh2[u + 1], hs[u + 1], h1);
            h2 = fmaf(whh2[u + 2], hs[u + 2], h2);
            h3 = fmaf(whh2[u + 3], hs[u + 3], h3);
        }
        float gh = (h0 + h1) + (h2 + h3);
        v2f accA = {bi2, 0.f}, accB = {0.f, 0.f};
        #pragma unroll
        for (int q = 0; q < FDIM/2; q += 2) {
            accA = __builtin_elementwise_fma(wih2p[q],     xs2[q],     accA);
            accB = __builtin_elementwise_fma(wih2p[q + 1], xs2[q + 1], accB);
        }
        float gi = (accA.x + accB.x) + (accA.y + accB.y);
        float v   = gi + gh;
        float vz  = __shfl(v,  (lane + 20) & 63);
        float in_ = __shfl(gi, (lane + 40) & 63);
        float hn  = __shfl(gh, (lane + 40) & 63);
        float r = fast_sigmoid(v);
        float z = fast_sigmoid(vz);
        float n = fast_tanh(fmaf(r, hn, in_));
        float hraw = n + z * (hvd - n);
        hvd = fast_tanh(hraw);
        #pragma unroll
        for (int u = 0; u < HID; u++) hs[u] = READLANE_F(hvd, u);
        float a0 = bf, a1 = 0.f, a2 = 0.f, a3 = 0.f;
        #pragma unroll
        for (int u = 0; u < HID; u += 4) {
            a0 = fmaf(wfc[u + 0], hs[u + 0], a0);
            a1 = fmaf(wfc[u + 1], hs[u + 1], a1);
            a2 = fmaf(wfc[u + 2], hs[u + 2], a2);
            a3 = fmaf(wfc[u + 3], hs[u + 3], a3);
        }
        xv = fast_tanh((a0 + a1) + (a2 + a3));
        if (lane < FDIM) orow[lane] = xv;
        xsh[wslot][lane] = xv;
    }
}

extern "C" void kernel_launch(void* const* d_in, const int* in_sizes, int n_in,
                              void* d_out, int out_size, void* d_ws, size_t ws_size,
                              hipStream_t stream) {
    const float* x    = (const float*)d_in[0];
    const int*   oh   = (const int*)d_in[1];
    const float* e0   = (const float*)d_in[2];
    const float* e1   = (const float*)d_in[3];
    const float* e2   = (const float*)d_in[4];
    const float* e3   = (const float*)d_in[5];
    const float* Wih1 = (const float*)d_in[6];
    const float* Whh1 = (const float*)d_in[7];
    const float* bih1 = (const float*)d_in[8];
    const float* bhh1 = (const float*)d_in[9];
    const float* Wih2 = (const float*)d_in[10];
    const float* Whh2 = (const float*)d_in[11];
    const float* bih2 = (const float*)d_in[12];
    const float* bhh2 = (const float*)d_in[13];
    const float* Wfc  = (const float*)d_in[14];
    const float* bfc  = (const float*)d_in[15];

    float* out    = (float*)d_out;
    float* origin = out;
    float* out2   = out + (size_t)BATCH * SEQ * FDIM;
    float* gibuf  = (float*)d_ws;

    const size_t gi_bytes = (size_t)BATCH * SEQ * GIPAD * sizeof(float);
    const int prep_blocks = NROWS / (4 * PROWS);   // 16 rows/wave, 4 waves/block

    if (ws_size >= gi_bytes) {
        prep_kernel<true><<<prep_blocks, 256, 0, stream>>>(x, oh, e0, e1, e2, e3,
                                                           Wih1, bih1, origin, gibuf);
        gru_kernel<true><<<(BATCH * 64) / 256, 256, 0, stream>>>(origin, gibuf,
            Wih1, Whh1, bih1, bhh1, Wih2, Whh2, bih2, bhh2, Wfc, bfc, out2);
    } else {
        prep_kernel<false><<<prep_blocks, 256, 0, stream>>>(x, oh, e0, e1, e2, e3,
                                                            Wih1, bih1, origin, gibuf);
        gru_kernel<false><<<(BATCH * 64) / 256, 256, 0, stream>>>(origin, gibuf,
            Wih1, Whh1, bih1, bhh1, Wih2, Whh2, bih2, bhh2, Wfc, bfc, out2);
    }
}